// Round 1
// baseline (1049.343 us; speedup 1.0000x reference)
//
#include <hip/hip_runtime.h>
#include <hip/hip_bf16.h>

// Problem constants
#define NN 10000
#define EE 160000
#define IN_DIM 128
#define HID 128
#define HEADS 8
#define F1 (HEADS*HID)   // 1024
#define INT_DIM 512
#define OUT_DIM 3

// ---------------- CSR build ----------------
__global__ __launch_bounds__(256) void count_kernel(const int* __restrict__ dst, int E, int* __restrict__ cnt){
    int e = blockIdx.x*256 + threadIdx.x;
    if(e < E) atomicAdd(&cnt[dst[e]], 1);
}

__global__ __launch_bounds__(256) void scan_kernel(const int* __restrict__ cnt, int* __restrict__ rowp,
                                                   int* __restrict__ cursor, int n){
    __shared__ int sh[256];
    __shared__ int stotal;
    int t = threadIdx.x;
    if(t==0) stotal = 0;
    __syncthreads();
    for(int base=0; base<n; base+=256){
        int i = base + t;
        int v = (i<n) ? cnt[i] : 0;
        sh[t] = v;
        __syncthreads();
        #pragma unroll
        for(int off=1; off<256; off<<=1){
            int add = (t>=off) ? sh[t-off] : 0;
            __syncthreads();
            sh[t] += add;
            __syncthreads();
        }
        int excl = sh[t] - v;
        if(i<n){ rowp[i] = stotal + excl; cursor[i] = stotal + excl; }
        int chunk_total = sh[255];
        __syncthreads();
        if(t==0) stotal += chunk_total;
        __syncthreads();
    }
    if(t==0) rowp[n] = stotal;
}

__global__ __launch_bounds__(256) void fill_kernel(const int* __restrict__ src, const int* __restrict__ dst,
                                                   int E, int* __restrict__ cursor, int* __restrict__ colsrc){
    int e = blockIdx.x*256 + threadIdx.x;
    if(e < E){
        int d = dst[e];
        int pos = atomicAdd(&cursor[d], 1);
        colsrc[pos] = src[e];
    }
}

// ---------------- fp32 tiled GEMM: C[M,N] = A[M,K] @ B[K,N], optional bias+relu ----------------
__global__ __launch_bounds__(256) void gemm_kernel(const float* __restrict__ A, const float* __restrict__ B,
                                                   const float* __restrict__ bias, float* __restrict__ C,
                                                   int M, int Nn, int K, int fuse){
    __shared__ float As[16][68];
    __shared__ float Bs[16][68];
    int tid = threadIdx.x;
    int tx = tid & 15, ty = tid >> 4;
    int row0 = blockIdx.y*64, col0 = blockIdx.x*64;
    float acc[4][4];
    #pragma unroll
    for(int i=0;i<4;i++)
        #pragma unroll
        for(int j=0;j<4;j++) acc[i][j]=0.f;

    for(int k0=0; k0<K; k0+=16){
        #pragma unroll
        for(int i=0;i<4;i++){
            int idx = tid + i*256;
            int m = idx >> 4, kk = idx & 15;
            int r = row0 + m;
            As[kk][m] = (r < M) ? A[(size_t)r*K + k0 + kk] : 0.f;
        }
        #pragma unroll
        for(int i=0;i<4;i++){
            int idx = tid + i*256;
            int n = idx & 63, kk = idx >> 6;
            int c = col0 + n;
            Bs[kk][n] = (c < Nn) ? B[(size_t)(k0+kk)*Nn + c] : 0.f;
        }
        __syncthreads();
        #pragma unroll
        for(int kk=0; kk<16; kk++){
            float ra[4], rb[4];
            #pragma unroll
            for(int i=0;i<4;i++) ra[i] = As[kk][ty*4+i];
            #pragma unroll
            for(int j=0;j<4;j++) rb[j] = Bs[kk][tx*4+j];
            #pragma unroll
            for(int i=0;i<4;i++)
                #pragma unroll
                for(int j=0;j<4;j++) acc[i][j] += ra[i]*rb[j];
        }
        __syncthreads();
    }
    #pragma unroll
    for(int i=0;i<4;i++){
        int r = row0 + ty*4 + i;
        if(r < M){
            #pragma unroll
            for(int j=0;j<4;j++){
                int c = col0 + tx*4 + j;
                if(c < Nn){
                    float v = acc[i][j];
                    if(fuse){ v += bias[c]; v = fmaxf(v, 0.f); }
                    C[(size_t)r*Nn + c] = v;
                }
            }
        }
    }
}

// ---------------- alpha: per-node per-head dot(h[n,h,:], a[h,:]) ----------------
template<int H, int C>
__global__ __launch_bounds__(128) void alpha_kernel(const float* __restrict__ hbuf,
                                                    const float* __restrict__ a_src,
                                                    const float* __restrict__ a_dst,
                                                    float* __restrict__ asrc, float* __restrict__ adst, int n){
    constexpr int F = H*C;
    int node = blockIdx.x;
    int t = threadIdx.x;          // 128 threads
    float ps[H], pd[H];
    #pragma unroll
    for(int h=0;h<H;h++){ ps[h]=0.f; pd[h]=0.f; }
    #pragma unroll
    for(int k=0;k<F/128;k++){
        int idx = t + k*128;
        constexpr_int:
        ;
        int h = (k*128)/C;        // valid since t<128 <= C
        float v = hbuf[(size_t)node*F + idx];
        ps[h] += v * a_src[idx];
        pd[h] += v * a_dst[idx];
    }
    int lane = t & 63, wv = t >> 6;
    __shared__ float shs[2][H], shd[2][H];
    #pragma unroll
    for(int h=0;h<H;h++){
        float v = ps[h], w = pd[h];
        #pragma unroll
        for(int off=32; off; off>>=1){ v += __shfl_down(v, off); w += __shfl_down(w, off); }
        if(lane==0){ shs[wv][h]=v; shd[wv][h]=w; }
    }
    __syncthreads();
    if(t < H){
        asrc[(size_t)node*H + t] = shs[0][t] + shs[1][t];
        adst[(size_t)node*H + t] = shd[0][t] + shd[1][t];
    }
}

// ---------------- aggregation: out[n,f] = relu( sum_e ee*h[src,f] / sum_e ee + b[f] ) ----------------
template<int H, int C>
__global__ __launch_bounds__(256) void agg_kernel(const float* __restrict__ hbuf,
                                                  const float* __restrict__ asrc,
                                                  const float* __restrict__ adst,
                                                  const int* __restrict__ rowp,
                                                  const int* __restrict__ colsrc,
                                                  const float* __restrict__ bias,
                                                  float* __restrict__ out, int n){
    constexpr int F = H*C;
    constexpr int PER = F/256;
    int node = blockIdx.x;
    int t = threadIdx.x;
    __shared__ float sh_ee[64][H];
    __shared__ int   sh_src[64];
    __shared__ float sh_adst[H];
    __shared__ float sh_red[256];
    __shared__ float sh_denom[H];
    if(t < H) sh_adst[t] = adst[(size_t)node*H + t];
    int beg = rowp[node], end = rowp[node+1];
    float acc[PER];
    #pragma unroll
    for(int k=0;k<PER;k++) acc[k]=0.f;
    float dpart = 0.f;
    const int hh = t % H;        // constant per thread (stride 256 divisible by H)
    for(int base=beg; base<end; base+=64){
        int clen = min(64, end-base);
        __syncthreads();   // protect previous chunk's LDS reads; makes sh_adst visible on first iter
        if(t < clen) sh_src[t] = colsrc[base + t];
        int items = clen * H;
        for(int it=t; it<items; it+=256){
            int j = it / H;
            int s = colsrc[base + j];
            float e = asrc[(size_t)s*H + hh] + sh_adst[hh];
            e = (e > 0.f) ? e : 0.2f*e;
            float ee = expf(e);
            sh_ee[j][hh] = ee;
            dpart += ee;
        }
        __syncthreads();
        for(int j=0;j<clen;j++){
            int s = sh_src[j];
            const float* hrow = hbuf + (size_t)s*F;
            #pragma unroll
            for(int k=0;k<PER;k++){
                int f = t + k*256;
                acc[k] += hrow[f] * sh_ee[j][f / C];
            }
        }
    }
    sh_red[t] = dpart;
    __syncthreads();
    if(t < H){
        float s = 0.f;
        for(int i=t; i<256; i+=H) s += sh_red[i];
        sh_denom[t] = s;
    }
    __syncthreads();
    #pragma unroll
    for(int k=0;k<PER;k++){
        int f = t + k*256;
        float denom = sh_denom[f / C] + 1e-16f;
        float v = acc[k]/denom + bias[f];
        out[(size_t)node*F + f] = fmaxf(v, 0.f);
    }
}

// ---------------- classifier: out[n,3] = h[n,:512] @ Wc + bc ----------------
__global__ __launch_bounds__(256) void cls_kernel(const float* __restrict__ h, const float* __restrict__ Wc,
                                                  const float* __restrict__ bc, float* __restrict__ out, int n){
    int node = blockIdx.x*4 + (threadIdx.x >> 6);
    int lane = threadIdx.x & 63;
    if(node >= n) return;
    float s0=0.f, s1=0.f, s2=0.f;
    const float* hr = h + (size_t)node*INT_DIM;
    for(int k=lane; k<INT_DIM; k+=64){
        float v = hr[k];
        s0 += v * Wc[k*3+0];
        s1 += v * Wc[k*3+1];
        s2 += v * Wc[k*3+2];
    }
    #pragma unroll
    for(int off=32; off; off>>=1){
        s0 += __shfl_down(s0, off);
        s1 += __shfl_down(s1, off);
        s2 += __shfl_down(s2, off);
    }
    if(lane==0){
        out[(size_t)node*3+0] = s0 + bc[0];
        out[(size_t)node*3+1] = s1 + bc[1];
        out[(size_t)node*3+2] = s2 + bc[2];
    }
}

extern "C" void kernel_launch(void* const* d_in, const int* in_sizes, int n_in,
                              void* d_out, int out_size, void* d_ws, size_t ws_size,
                              hipStream_t stream){
    const float* x      = (const float*)d_in[0];
    const int*   ei     = (const int*)d_in[1];
    const float* W1     = (const float*)d_in[2];
    const float* a_src1 = (const float*)d_in[3];
    const float* a_dst1 = (const float*)d_in[4];
    const float* b1     = (const float*)d_in[5];
    const float* W2     = (const float*)d_in[6];
    const float* a_src2 = (const float*)d_in[7];
    const float* a_dst2 = (const float*)d_in[8];
    const float* b2     = (const float*)d_in[9];
    const float* W3     = (const float*)d_in[10];
    const float* a_src3 = (const float*)d_in[11];
    const float* a_dst3 = (const float*)d_in[12];
    const float* b3     = (const float*)d_in[13];
    const float* Wl     = (const float*)d_in[14];
    const float* bl     = (const float*)d_in[15];
    const float* Wc     = (const float*)d_in[16];
    const float* bc     = (const float*)d_in[17];
    float* out = (float*)d_out;

    const int* src = ei;
    const int* dst = ei + EE;

    // workspace carve (floats then ints)
    float* bufA = (float*)d_ws;                    // 10,240,000 f
    float* bufB = bufA + (size_t)NN*F1;            // 10,240,000 f
    float* asrc = bufB + (size_t)NN*F1;            // 80,000 f
    float* adst = asrc + (size_t)NN*HEADS;         // 80,000 f
    int* cnt    = (int*)(adst + (size_t)NN*HEADS); // 10,000 i
    int* rowp   = cnt + NN;                        // 10,001 i
    int* cursor = rowp + (NN+1);                   // 10,000 i
    int* colsrc = cursor + NN;                     // 160,000 i

    // ---- CSR build (by dst) ----
    hipMemsetAsync(cnt, 0, NN*sizeof(int), stream);
    count_kernel<<<(EE+255)/256, 256, 0, stream>>>(dst, EE, cnt);
    scan_kernel<<<1, 256, 0, stream>>>(cnt, rowp, cursor, NN);
    fill_kernel<<<(EE+255)/256, 256, 0, stream>>>(src, dst, EE, cursor, colsrc);

    dim3 blk(256);
    // ---- Layer 1: x[10000,128] @ W1[128,1024] ----
    gemm_kernel<<<dim3(F1/64, (NN+63)/64), blk, 0, stream>>>(x, W1, nullptr, bufA, NN, F1, IN_DIM, 0);
    alpha_kernel<HEADS, HID><<<NN, 128, 0, stream>>>(bufA, a_src1, a_dst1, asrc, adst, NN);
    agg_kernel<HEADS, HID><<<NN, 256, 0, stream>>>(bufA, asrc, adst, rowp, colsrc, b1, bufB, NN);

    // ---- Layer 2: bufB[10000,1024] @ W2[1024,1024] ----
    gemm_kernel<<<dim3(F1/64, (NN+63)/64), blk, 0, stream>>>(bufB, W2, nullptr, bufA, NN, F1, F1, 0);
    alpha_kernel<HEADS, HID><<<NN, 128, 0, stream>>>(bufA, a_src2, a_dst2, asrc, adst, NN);
    agg_kernel<HEADS, HID><<<NN, 256, 0, stream>>>(bufA, asrc, adst, rowp, colsrc, b2, bufB, NN);

    // ---- Layer 3: bufB[10000,1024] @ W3[1024,512], heads=1 ch=512 ----
    gemm_kernel<<<dim3(INT_DIM/64, (NN+63)/64), blk, 0, stream>>>(bufB, W3, nullptr, bufA, NN, INT_DIM, F1, 0);
    alpha_kernel<1, INT_DIM><<<NN, 128, 0, stream>>>(bufA, a_src3, a_dst3, asrc, adst, NN);
    agg_kernel<1, INT_DIM><<<NN, 256, 0, stream>>>(bufA, asrc, adst, rowp, colsrc, b3, bufB, NN);

    // ---- Linear: relu(bufB[10000,512] @ Wl[512,512] + bl) ----
    gemm_kernel<<<dim3(INT_DIM/64, (NN+63)/64), blk, 0, stream>>>(bufB, Wl, bl, bufA, NN, INT_DIM, INT_DIM, 1);

    // ---- Classifier: bufA[10000,512] @ Wc[512,3] + bc ----
    cls_kernel<<<(NN+3)/4, 256, 0, stream>>>(bufA, Wc, bc, out, NN);
}

// Round 3
// 593.669 us; speedup vs baseline: 1.7676x; 1.7676x over previous
//
#include <hip/hip_runtime.h>
#include <hip/hip_bf16.h>

// Problem constants
#define NN 10000
#define EE 160000
#define IN_DIM 128
#define HID 128
#define HEADS 8
#define F1 (HEADS*HID)   // 1024
#define INT_DIM 512
#define OUT_DIM 3
#define MPAD 10112       // 79 * 128

typedef __attribute__((ext_vector_type(8))) short bf16x8;
typedef __attribute__((ext_vector_type(4))) float f32x4;

__device__ inline short f2bf(float v){
    union { __hip_bfloat16 b; short s; } u;
    u.b = __float2bfloat16(v);
    return u.s;
}
__device__ inline float bf2f(short s){
    union { short s; __hip_bfloat16 b; } u;
    u.s = s;
    return __bfloat162float(u.b);
}

// ---------------- CSR build ----------------
__global__ __launch_bounds__(256) void count_kernel(const int* __restrict__ dst, int E, int* __restrict__ cnt){
    int e = blockIdx.x*256 + threadIdx.x;
    if(e < E) atomicAdd(&cnt[dst[e]], 1);
}

__global__ __launch_bounds__(256) void scan_kernel(const int* __restrict__ cnt, int* __restrict__ rowp,
                                                   int* __restrict__ cursor, int n){
    __shared__ int sh[256];
    __shared__ int stotal;
    int t = threadIdx.x;
    if(t==0) stotal = 0;
    __syncthreads();
    for(int base=0; base<n; base+=256){
        int i = base + t;
        int v = (i<n) ? cnt[i] : 0;
        sh[t] = v;
        __syncthreads();
        #pragma unroll
        for(int off=1; off<256; off<<=1){
            int add = (t>=off) ? sh[t-off] : 0;
            __syncthreads();
            sh[t] += add;
            __syncthreads();
        }
        int excl = sh[t] - v;
        if(i<n){ rowp[i] = stotal + excl; cursor[i] = stotal + excl; }
        int chunk_total = sh[255];
        __syncthreads();
        if(t==0) stotal += chunk_total;
        __syncthreads();
    }
    if(t==0) rowp[n] = stotal;
}

__global__ __launch_bounds__(256) void fill_kernel(const int* __restrict__ src, const int* __restrict__ dst,
                                                   int E, int* __restrict__ cursor, int* __restrict__ colsrc){
    int e = blockIdx.x*256 + threadIdx.x;
    if(e < E){
        int d = dst[e];
        int pos = atomicAdd(&cursor[d], 1);
        colsrc[pos] = src[e];
    }
}

// ---------------- split fp32 -> (hi,lo) bf16, flat ----------------
__global__ __launch_bounds__(256) void split_rows_kernel(const float* __restrict__ X, short* __restrict__ Xh,
                                                         short* __restrict__ Xl, int n4){
    int i = blockIdx.x*256 + threadIdx.x;
    if(i >= n4) return;
    float4 v = ((const float4*)X)[i];
    short4 h, l;
    h.x = f2bf(v.x); l.x = f2bf(v.x - bf2f(h.x));
    h.y = f2bf(v.y); l.y = f2bf(v.y - bf2f(h.y));
    h.z = f2bf(v.z); l.z = f2bf(v.z - bf2f(h.z));
    h.w = f2bf(v.w); l.w = f2bf(v.w - bf2f(h.w));
    ((short4*)Xh)[i] = h;
    ((short4*)Xl)[i] = l;
}

// ---------------- split + transpose weights: B[K,N] fp32 -> T_hi/T_lo [N,K] bf16 ----------------
__global__ __launch_bounds__(256) void splitT_kernel(const float* __restrict__ B, short* __restrict__ Th,
                                                     short* __restrict__ Tl, int K, int N){
    __shared__ float tile[32][33];
    const int tx = threadIdx.x & 31, ty = threadIdx.x >> 5;   // 32 x 8
    const int n0 = blockIdx.x * 32, k0 = blockIdx.y * 32;
    #pragma unroll
    for(int i = 0; i < 32; i += 8)
        tile[ty + i][tx] = B[(size_t)(k0 + ty + i) * N + n0 + tx];
    __syncthreads();
    #pragma unroll
    for(int i = 0; i < 32; i += 8){
        int n = ty + i;
        float v = tile[tx][n];             // = B[k0+tx][n0+n]
        short hv = f2bf(v);
        Th[(size_t)(n0 + n) * K + k0 + tx] = hv;
        Tl[(size_t)(n0 + n) * K + k0 + tx] = f2bf(v - bf2f(hv));
    }
}

// ---------------- split-bf16 MFMA GEMM: C[M,N] = (Ah+Al)[M,K] @ (Bh+Bl)^T[N,K]^T ----------------
// 128x128 tile, BK=32, 4 waves (2x2), 16x16x32 bf16 MFMA, global_load_lds staging with
// XOR-swizzled source (slot ^= row&3 within each 64B row) + swizzled ds_read_b128.
template<int FUSE>
__global__ __launch_bounds__(256) void mfma_gemm_kernel(
    const short* __restrict__ Ah, const short* __restrict__ Al,
    const short* __restrict__ Bh, const short* __restrict__ Bl,
    const float* __restrict__ bias, float* __restrict__ C, int N, int K)
{
    __shared__ short lA[128*32];   // 8 KB
    __shared__ short lB[128*32];   // 8 KB
    const int tid  = threadIdx.x;
    const int lane = tid & 63;
    const int w    = tid >> 6;
    const int wm   = w >> 1, wn = w & 1;
    const int row0 = blockIdx.y * 128, col0 = blockIdx.x * 128;

    f32x4 acc[4][4];
    #pragma unroll
    for(int i=0;i<4;i++)
        #pragma unroll
        for(int j=0;j<4;j++) acc[i][j] = (f32x4){0.f,0.f,0.f,0.f};

    // staging source addresses (chunk c1 = tid -> rows 0..63, c2 = tid+256 -> rows 64..127)
    const int r1 = tid >> 2,  s1 = (tid & 3) ^ (r1 & 3);
    const int r2 = r1 + 64,   s2 = (tid & 3) ^ (r2 & 3);
    const int aoff1 = (row0 + r1) * K + s1 * 8;
    const int aoff2 = (row0 + r2) * K + s2 * 8;
    const int boff1 = (col0 + r1) * K + s1 * 8;
    const int boff2 = (col0 + r2) * K + s2 * 8;

    typedef __attribute__((address_space(3))) char lds_char;
    lds_char* lA1 = (lds_char*)(&lA[0]) + w * 1024;
    lds_char* lA2 = (lds_char*)(&lA[0]) + w * 1024 + 4096;
    lds_char* lB1 = (lds_char*)(&lB[0]) + w * 1024;
    lds_char* lB2 = (lds_char*)(&lB[0]) + w * 1024 + 4096;

    // fragment read byte-offsets (swizzled)
    int arow[4], brow[4];
    const int slotx = ((lane >> 4) ^ (lane & 3)) << 4;
    #pragma unroll
    for(int i=0;i<4;i++){
        arow[i] = (wm*64 + i*16 + (lane & 15)) * 64 + slotx;
        brow[i] = (wn*64 + i*16 + (lane & 15)) * 64 + slotx;
    }

    #pragma unroll 1
    for(int pass = 0; pass < 3; ++pass){
        const short* Ap = (pass == 2) ? Al : Ah;
        const short* Bp = (pass == 1) ? Bl : Bh;
        #pragma unroll 1
        for(int k0 = 0; k0 < K; k0 += 32){
            __syncthreads();
            __builtin_amdgcn_global_load_lds((__attribute__((address_space(1))) void*)(Ap + aoff1 + k0),
                                             (__attribute__((address_space(3))) void*)lA1, 16, 0, 0);
            __builtin_amdgcn_global_load_lds((__attribute__((address_space(1))) void*)(Ap + aoff2 + k0),
                                             (__attribute__((address_space(3))) void*)lA2, 16, 0, 0);
            __builtin_amdgcn_global_load_lds((__attribute__((address_space(1))) void*)(Bp + boff1 + k0),
                                             (__attribute__((address_space(3))) void*)lB1, 16, 0, 0);
            __builtin_amdgcn_global_load_lds((__attribute__((address_space(1))) void*)(Bp + boff2 + k0),
                                             (__attribute__((address_space(3))) void*)lB2, 16, 0, 0);
            __syncthreads();
            bf16x8 af[4], bfr[4];
            #pragma unroll
            for(int i=0;i<4;i++) af[i]  = *(const bf16x8*)((const char*)lA + arow[i]);
            #pragma unroll
            for(int j=0;j<4;j++) bfr[j] = *(const bf16x8*)((const char*)lB + brow[j]);
            #pragma unroll
            for(int i=0;i<4;i++)
                #pragma unroll
                for(int j=0;j<4;j++)
                    acc[i][j] = __builtin_amdgcn_mfma_f32_16x16x32_bf16(af[i], bfr[j], acc[i][j], 0, 0, 0);
        }
    }

    // epilogue: C/D layout col=lane&15, row=(lane>>4)*4+reg
    #pragma unroll
    for(int i=0;i<4;i++){
        const int rr = row0 + wm*64 + i*16 + ((lane >> 4) << 2);
        #pragma unroll
        for(int j=0;j<4;j++){
            const int cc = col0 + wn*64 + j*16 + (lane & 15);
            float b = FUSE ? bias[cc] : 0.f;
            #pragma unroll
            for(int r=0;r<4;r++){
                float v = acc[i][j][r];
                if(FUSE) v = fmaxf(v + b, 0.f);
                C[(size_t)(rr + r) * N + cc] = v;
            }
        }
    }
}

// ---------------- alpha: per-node per-head dot(h[n,h,:], a[h,:]) ----------------
template<int H, int C>
__global__ __launch_bounds__(128) void alpha_kernel(const float* __restrict__ hbuf,
                                                    const float* __restrict__ a_src,
                                                    const float* __restrict__ a_dst,
                                                    float* __restrict__ asrc, float* __restrict__ adst, int n){
    constexpr int F = H*C;
    int node = blockIdx.x;
    int t = threadIdx.x;          // 128 threads
    float ps[H], pd[H];
    #pragma unroll
    for(int h=0;h<H;h++){ ps[h]=0.f; pd[h]=0.f; }
    #pragma unroll
    for(int k=0;k<F/128;k++){
        int idx = t + k*128;
        int h = (k*128)/C;        // valid since t<128 <= C
        float v = hbuf[(size_t)node*F + idx];
        ps[h] += v * a_src[idx];
        pd[h] += v * a_dst[idx];
    }
    int lane = t & 63, wv = t >> 6;
    __shared__ float shs[2][H], shd[2][H];
    #pragma unroll
    for(int h=0;h<H;h++){
        float v = ps[h], w2 = pd[h];
        #pragma unroll
        for(int off=32; off; off>>=1){ v += __shfl_down(v, off); w2 += __shfl_down(w2, off); }
        if(lane==0){ shs[wv][h]=v; shd[wv][h]=w2; }
    }
    __syncthreads();
    if(t < H){
        asrc[(size_t)node*H + t] = shs[0][t] + shs[1][t];
        adst[(size_t)node*H + t] = shd[0][t] + shd[1][t];
    }
}

// ---------------- aggregation: g = relu( softmax-agg(h) + b ), emits split bf16 hi/lo ----------------
template<int H, int C>
__global__ __launch_bounds__(256) void agg_kernel(const float* __restrict__ hbuf,
                                                  const float* __restrict__ asrc,
                                                  const float* __restrict__ adst,
                                                  const int* __restrict__ rowp,
                                                  const int* __restrict__ colsrc,
                                                  const float* __restrict__ bias,
                                                  short* __restrict__ gh, short* __restrict__ gl, int n){
    constexpr int F = H*C;
    constexpr int PER = F/256;
    int node = blockIdx.x;
    int t = threadIdx.x;
    __shared__ float sh_ee[64][H];
    __shared__ int   sh_src[64];
    __shared__ float sh_adst[H];
    __shared__ float sh_red[256];
    __shared__ float sh_denom[H];
    if(t < H) sh_adst[t] = adst[(size_t)node*H + t];
    int beg = rowp[node], end = rowp[node+1];
    float acc[PER];
    #pragma unroll
    for(int k=0;k<PER;k++) acc[k]=0.f;
    float dpart = 0.f;
    const int hh = t % H;
    for(int base=beg; base<end; base+=64){
        int clen = min(64, end-base);
        __syncthreads();
        if(t < clen) sh_src[t] = colsrc[base + t];
        int items = clen * H;
        for(int it=t; it<items; it+=256){
            int j = it / H;
            int s = colsrc[base + j];
            float e = asrc[(size_t)s*H + hh] + sh_adst[hh];
            e = (e > 0.f) ? e : 0.2f*e;
            float ee = expf(e);
            sh_ee[j][hh] = ee;
            dpart += ee;
        }
        __syncthreads();
        for(int j=0;j<clen;j++){
            int s = sh_src[j];
            const float* hrow = hbuf + (size_t)s*F;
            #pragma unroll
            for(int k=0;k<PER;k++){
                int f = t + k*256;
                acc[k] += hrow[f] * sh_ee[j][f / C];
            }
        }
    }
    sh_red[t] = dpart;
    __syncthreads();
    if(t < H){
        float s = 0.f;
        for(int i=t; i<256; i+=H) s += sh_red[i];
        sh_denom[t] = s;
    }
    __syncthreads();
    #pragma unroll
    for(int k=0;k<PER;k++){
        int f = t + k*256;
        float denom = sh_denom[f / C] + 1e-16f;
        float v = fmaxf(acc[k]/denom + bias[f], 0.f);
        short hv = f2bf(v);
        gh[(size_t)node*F + f] = hv;
        gl[(size_t)node*F + f] = f2bf(v - bf2f(hv));
    }
}

// ---------------- classifier: out[n,3] = h[n,:512] @ Wc + bc ----------------
__global__ __launch_bounds__(256) void cls_kernel(const float* __restrict__ h, const float* __restrict__ Wc,
                                                  const float* __restrict__ bc, float* __restrict__ out, int n){
    int node = blockIdx.x*4 + (threadIdx.x >> 6);
    int lane = threadIdx.x & 63;
    if(node >= n) return;
    float s0=0.f, s1=0.f, s2=0.f;
    const float* hr = h + (size_t)node*INT_DIM;
    for(int k=lane; k<INT_DIM; k+=64){
        float v = hr[k];
        s0 += v * Wc[k*3+0];
        s1 += v * Wc[k*3+1];
        s2 += v * Wc[k*3+2];
    }
    #pragma unroll
    for(int off=32; off; off>>=1){
        s0 += __shfl_down(s0, off);
        s1 += __shfl_down(s1, off);
        s2 += __shfl_down(s2, off);
    }
    if(lane==0){
        out[(size_t)node*3+0] = s0 + bc[0];
        out[(size_t)node*3+1] = s1 + bc[1];
        out[(size_t)node*3+2] = s2 + bc[2];
    }
}

extern "C" void kernel_launch(void* const* d_in, const int* in_sizes, int n_in,
                              void* d_out, int out_size, void* d_ws, size_t ws_size,
                              hipStream_t stream){
    const float* x      = (const float*)d_in[0];
    const int*   ei     = (const int*)d_in[1];
    const float* W1     = (const float*)d_in[2];
    const float* a_src1 = (const float*)d_in[3];
    const float* a_dst1 = (const float*)d_in[4];
    const float* b1     = (const float*)d_in[5];
    const float* W2     = (const float*)d_in[6];
    const float* a_src2 = (const float*)d_in[7];
    const float* a_dst2 = (const float*)d_in[8];
    const float* b2     = (const float*)d_in[9];
    const float* W3     = (const float*)d_in[10];
    const float* a_src3 = (const float*)d_in[11];
    const float* a_dst3 = (const float*)d_in[12];
    const float* b3     = (const float*)d_in[13];
    const float* Wl     = (const float*)d_in[14];
    const float* bl     = (const float*)d_in[15];
    const float* Wc     = (const float*)d_in[16];
    const float* bc     = (const float*)d_in[17];
    float* out = (float*)d_out;

    const int* src = ei;
    const int* dst = ei + EE;

    // workspace carve
    char* p = (char*)d_ws;
    float* hbuf = (float*)p;  p += (size_t)MPAD*F1*4;   // 41.4 MB
    short* g_hi = (short*)p;  p += (size_t)MPAD*F1*2;   // 20.7 MB
    short* g_lo = (short*)p;  p += (size_t)MPAD*F1*2;   // 20.7 MB
    short* wt_h = (short*)p;  p += (size_t)F1*F1*2;     // 2.1 MB
    short* wt_l = (short*)p;  p += (size_t)F1*F1*2;     // 2.1 MB
    float* asrc = (float*)p;  p += (size_t)NN*HEADS*4;
    float* adst = (float*)p;  p += (size_t)NN*HEADS*4;
    int* cnt    = (int*)p;    p += NN*4;
    int* rowp   = (int*)p;    p += (NN+1)*4;
    int* cursor = (int*)p;    p += NN*4;
    int* colsrc = (int*)p;    p += EE*4;
    // x split overlays g region (g written only after GEMM1 consumed xs)
    short* xs_h = g_hi;
    short* xs_l = g_lo;

    // ---- CSR build (by dst) ----
    hipMemsetAsync(cnt, 0, NN*sizeof(int), stream);
    count_kernel<<<(EE+255)/256, 256, 0, stream>>>(dst, EE, cnt);
    scan_kernel<<<1, 256, 0, stream>>>(cnt, rowp, cursor, NN);
    fill_kernel<<<(EE+255)/256, 256, 0, stream>>>(src, dst, EE, cursor, colsrc);

    // ---- Layer 1 ----
    split_rows_kernel<<<(NN*IN_DIM/4 + 255)/256, 256, 0, stream>>>(x, xs_h, xs_l, NN*IN_DIM/4);
    splitT_kernel<<<dim3(F1/32, IN_DIM/32), 256, 0, stream>>>(W1, wt_h, wt_l, IN_DIM, F1);
    mfma_gemm_kernel<0><<<dim3(F1/128, MPAD/128), 256, 0, stream>>>(xs_h, xs_l, wt_h, wt_l, nullptr, hbuf, F1, IN_DIM);
    alpha_kernel<HEADS, HID><<<NN, 128, 0, stream>>>(hbuf, a_src1, a_dst1, asrc, adst, NN);
    agg_kernel<HEADS, HID><<<NN, 256, 0, stream>>>(hbuf, asrc, adst, rowp, colsrc, b1, g_hi, g_lo, NN);

    // ---- Layer 2 ----
    splitT_kernel<<<dim3(F1/32, F1/32), 256, 0, stream>>>(W2, wt_h, wt_l, F1, F1);
    mfma_gemm_kernel<0><<<dim3(F1/128, MPAD/128), 256, 0, stream>>>(g_hi, g_lo, wt_h, wt_l, nullptr, hbuf, F1, F1);
    alpha_kernel<HEADS, HID><<<NN, 128, 0, stream>>>(hbuf, a_src2, a_dst2, asrc, adst, NN);
    agg_kernel<HEADS, HID><<<NN, 256, 0, stream>>>(hbuf, asrc, adst, rowp, colsrc, b2, g_hi, g_lo, NN);

    // ---- Layer 3 (heads=1, ch=512) ----
    splitT_kernel<<<dim3(INT_DIM/32, F1/32), 256, 0, stream>>>(W3, wt_h, wt_l, F1, INT_DIM);
    mfma_gemm_kernel<0><<<dim3(INT_DIM/128, MPAD/128), 256, 0, stream>>>(g_hi, g_lo, wt_h, wt_l, nullptr, hbuf, INT_DIM, F1);
    alpha_kernel<1, INT_DIM><<<NN, 128, 0, stream>>>(hbuf, a_src3, a_dst3, asrc, adst, NN);
    agg_kernel<1, INT_DIM><<<NN, 256, 0, stream>>>(hbuf, asrc, adst, rowp, colsrc, b3, g_hi, g_lo, NN);

    // ---- Linear: relu(g3 @ Wl + bl) ----
    splitT_kernel<<<dim3(INT_DIM/32, INT_DIM/32), 256, 0, stream>>>(Wl, wt_h, wt_l, INT_DIM, INT_DIM);
    mfma_gemm_kernel<1><<<dim3(INT_DIM/128, MPAD/128), 256, 0, stream>>>(g_hi, g_lo, wt_h, wt_l, bl, hbuf, INT_DIM, INT_DIM);

    // ---- Classifier ----
    cls_kernel<<<(NN+3)/4, 256, 0, stream>>>(hbuf, Wc, bc, out, NN);
}

// Round 4
// 543.371 us; speedup vs baseline: 1.9312x; 1.0926x over previous
//
#include <hip/hip_runtime.h>
#include <hip/hip_bf16.h>

// Problem constants
#define NN 10000
#define EE 160000
#define IN_DIM 128
#define HID 128
#define HEADS 8
#define F1 (HEADS*HID)   // 1024
#define INT_DIM 512
#define OUT_DIM 3
#define MPAD 10112       // 79 * 128

typedef __attribute__((ext_vector_type(8))) short bf16x8;
typedef __attribute__((ext_vector_type(4))) float f32x4;

__device__ inline short f2bf(float v){
    union { __hip_bfloat16 b; short s; } u;
    u.b = __float2bfloat16(v);
    return u.s;
}
__device__ inline float bf2f(short s){
    union { short s; __hip_bfloat16 b; } u;
    u.s = s;
    return __bfloat162float(u.b);
}

// ---------------- CSR build ----------------
__global__ __launch_bounds__(256) void count_kernel(const int* __restrict__ dst, int E, int* __restrict__ cnt){
    int e = blockIdx.x*256 + threadIdx.x;
    if(e < E) atomicAdd(&cnt[dst[e]], 1);
}

__global__ __launch_bounds__(256) void scan_kernel(const int* __restrict__ cnt, int* __restrict__ rowp,
                                                   int* __restrict__ cursor, int n){
    __shared__ int sh[256];
    __shared__ int stotal;
    int t = threadIdx.x;
    if(t==0) stotal = 0;
    __syncthreads();
    for(int base=0; base<n; base+=256){
        int i = base + t;
        int v = (i<n) ? cnt[i] : 0;
        sh[t] = v;
        __syncthreads();
        #pragma unroll
        for(int off=1; off<256; off<<=1){
            int add = (t>=off) ? sh[t-off] : 0;
            __syncthreads();
            sh[t] += add;
            __syncthreads();
        }
        int excl = sh[t] - v;
        if(i<n){ rowp[i] = stotal + excl; cursor[i] = stotal + excl; }
        int chunk_total = sh[255];
        __syncthreads();
        if(t==0) stotal += chunk_total;
        __syncthreads();
    }
    if(t==0) rowp[n] = stotal;
}

__global__ __launch_bounds__(256) void fill_kernel(const int* __restrict__ src, const int* __restrict__ dst,
                                                   int E, int* __restrict__ cursor, int* __restrict__ colsrc){
    int e = blockIdx.x*256 + threadIdx.x;
    if(e < E){
        int d = dst[e];
        int pos = atomicAdd(&cursor[d], 1);
        colsrc[pos] = src[e];
    }
}

// ---------------- split fp32 -> (hi,lo) bf16, flat ----------------
__global__ __launch_bounds__(256) void split_rows_kernel(const float* __restrict__ X, short* __restrict__ Xh,
                                                         short* __restrict__ Xl, int n4){
    int i = blockIdx.x*256 + threadIdx.x;
    if(i >= n4) return;
    float4 v = ((const float4*)X)[i];
    short4 h, l;
    h.x = f2bf(v.x); l.x = f2bf(v.x - bf2f(h.x));
    h.y = f2bf(v.y); l.y = f2bf(v.y - bf2f(h.y));
    h.z = f2bf(v.z); l.z = f2bf(v.z - bf2f(h.z));
    h.w = f2bf(v.w); l.w = f2bf(v.w - bf2f(h.w));
    ((short4*)Xh)[i] = h;
    ((short4*)Xl)[i] = l;
}

// ---------------- split + transpose weights: B[K,N] fp32 -> T_hi/T_lo [N,K] bf16 ----------------
__global__ __launch_bounds__(256) void splitT_kernel(const float* __restrict__ B, short* __restrict__ Th,
                                                     short* __restrict__ Tl, int K, int N){
    __shared__ float tile[32][33];
    const int tx = threadIdx.x & 31, ty = threadIdx.x >> 5;   // 32 x 8
    const int n0 = blockIdx.x * 32, k0 = blockIdx.y * 32;
    #pragma unroll
    for(int i = 0; i < 32; i += 8)
        tile[ty + i][tx] = B[(size_t)(k0 + ty + i) * N + n0 + tx];
    __syncthreads();
    #pragma unroll
    for(int i = 0; i < 32; i += 8){
        int n = ty + i;
        float v = tile[tx][n];             // = B[k0+tx][n0+n]
        short hv = f2bf(v);
        Th[(size_t)(n0 + n) * K + k0 + tx] = hv;
        Tl[(size_t)(n0 + n) * K + k0 + tx] = f2bf(v - bf2f(hv));
    }
}

// ---------------- fused split-bf16 MFMA GEMM ----------------
// C = (Ah+Al) @ (Bh+Bl)^T via AhBh + AhBl + AlBh in ONE K-loop (48 MFMA / K-step).
// 128x128 tile, BK=32, 4 waves (2x2), global_load_lds width-16 staging, XOR-swizzled
// source + swizzled ds_read_b128, XCD-bijective 1D block swizzle.
template<int FUSE>
__global__ __launch_bounds__(256) void mfma_gemm_kernel(
    const short* __restrict__ Ah, const short* __restrict__ Al,
    const short* __restrict__ Bh, const short* __restrict__ Bl,
    const float* __restrict__ bias, float* __restrict__ C, int N, int K, int gx)
{
    __shared__ short lAh[128*32];   // 8 KB each
    __shared__ short lAl[128*32];
    __shared__ short lBh[128*32];
    __shared__ short lBl[128*32];
    const int tid  = threadIdx.x;
    const int lane = tid & 63;
    const int w    = tid >> 6;
    const int wm   = w >> 1, wn = w & 1;

    // XCD-bijective swizzle: each XCD gets a contiguous chunk of wgids
    const int nwg = gridDim.x;
    const int q = nwg >> 3, r = nwg & 7;
    const int xcd = blockIdx.x & 7, idx = blockIdx.x >> 3;
    const int wgid = (xcd < r ? xcd*(q+1) : r*(q+1) + (xcd-r)*q) + idx;
    const int row0 = (wgid / gx) * 128, col0 = (wgid % gx) * 128;

    f32x4 acc[4][4];
    #pragma unroll
    for(int i=0;i<4;i++)
        #pragma unroll
        for(int j=0;j<4;j++) acc[i][j] = (f32x4){0.f,0.f,0.f,0.f};

    // staging source addresses (chunk1 = rows 0..63, chunk2 = rows 64..127)
    const int r1 = tid >> 2,  s1 = (tid & 3) ^ (r1 & 3);
    const int r2 = r1 + 64,   s2 = (tid & 3) ^ (r2 & 3);
    const int aoff1 = (row0 + r1) * K + s1 * 8;
    const int aoff2 = (row0 + r2) * K + s2 * 8;
    const int boff1 = (col0 + r1) * K + s1 * 8;
    const int boff2 = (col0 + r2) * K + s2 * 8;

    typedef __attribute__((address_space(3))) char lds_char;
    lds_char* dAh1 = (lds_char*)(&lAh[0]) + w*1024;  lds_char* dAh2 = dAh1 + 4096;
    lds_char* dAl1 = (lds_char*)(&lAl[0]) + w*1024;  lds_char* dAl2 = dAl1 + 4096;
    lds_char* dBh1 = (lds_char*)(&lBh[0]) + w*1024;  lds_char* dBh2 = dBh1 + 4096;
    lds_char* dBl1 = (lds_char*)(&lBl[0]) + w*1024;  lds_char* dBl2 = dBl1 + 4096;

    // fragment read byte-offsets (swizzled)
    int arow[4], brow[4];
    const int slotx = ((lane >> 4) ^ (lane & 3)) << 4;
    #pragma unroll
    for(int i=0;i<4;i++){
        arow[i] = (wm*64 + i*16 + (lane & 15)) * 64 + slotx;
        brow[i] = (wn*64 + i*16 + (lane & 15)) * 64 + slotx;
    }

    #pragma unroll 1
    for(int k0 = 0; k0 < K; k0 += 32){
        __syncthreads();
        #define GLDS(src, dst) __builtin_amdgcn_global_load_lds( \
            (__attribute__((address_space(1))) void*)(src), \
            (__attribute__((address_space(3))) void*)(dst), 16, 0, 0)
        GLDS(Ah + aoff1 + k0, dAh1);  GLDS(Ah + aoff2 + k0, dAh2);
        GLDS(Al + aoff1 + k0, dAl1);  GLDS(Al + aoff2 + k0, dAl2);
        GLDS(Bh + boff1 + k0, dBh1);  GLDS(Bh + boff2 + k0, dBh2);
        GLDS(Bl + boff1 + k0, dBl1);  GLDS(Bl + boff2 + k0, dBl2);
        #undef GLDS
        __syncthreads();
        bf16x8 afh[4], afl[4];
        #pragma unroll
        for(int i=0;i<4;i++){
            afh[i] = *(const bf16x8*)((const char*)lAh + arow[i]);
            afl[i] = *(const bf16x8*)((const char*)lAl + arow[i]);
        }
        #pragma unroll
        for(int j=0;j<4;j++){
            bf16x8 bh = *(const bf16x8*)((const char*)lBh + brow[j]);
            bf16x8 bl = *(const bf16x8*)((const char*)lBl + brow[j]);
            #pragma unroll
            for(int i=0;i<4;i++){
                acc[i][j] = __builtin_amdgcn_mfma_f32_16x16x32_bf16(afh[i], bh, acc[i][j], 0, 0, 0);
                acc[i][j] = __builtin_amdgcn_mfma_f32_16x16x32_bf16(afh[i], bl, acc[i][j], 0, 0, 0);
                acc[i][j] = __builtin_amdgcn_mfma_f32_16x16x32_bf16(afl[i], bh, acc[i][j], 0, 0, 0);
            }
        }
    }

    // epilogue: C/D layout col=lane&15, row=(lane>>4)*4+reg
    #pragma unroll
    for(int i=0;i<4;i++){
        const int rr = row0 + wm*64 + i*16 + ((lane >> 4) << 2);
        #pragma unroll
        for(int j=0;j<4;j++){
            const int cc = col0 + wn*64 + j*16 + (lane & 15);
            float b = FUSE ? bias[cc] : 0.f;
            #pragma unroll
            for(int rg=0;rg<4;rg++){
                float v = acc[i][j][rg];
                if(FUSE) v = fmaxf(v + b, 0.f);
                C[(size_t)(rr + rg) * N + cc] = v;
            }
        }
    }
}

// ---------------- alpha: per-node per-head dot(h[n,h,:], a[h,:]) ----------------
template<int H, int C>
__global__ __launch_bounds__(128) void alpha_kernel(const float* __restrict__ hbuf,
                                                    const float* __restrict__ a_src,
                                                    const float* __restrict__ a_dst,
                                                    float* __restrict__ asrc, float* __restrict__ adst, int n){
    constexpr int F = H*C;
    int node = blockIdx.x;
    int t = threadIdx.x;          // 128 threads
    float ps[H], pd[H];
    #pragma unroll
    for(int h=0;h<H;h++){ ps[h]=0.f; pd[h]=0.f; }
    #pragma unroll
    for(int k=0;k<F/128;k++){
        int idx = t + k*128;
        int h = (k*128)/C;        // valid since t<128 <= C
        float v = hbuf[(size_t)node*F + idx];
        ps[h] += v * a_src[idx];
        pd[h] += v * a_dst[idx];
    }
    int lane = t & 63, wv = t >> 6;
    __shared__ float shs[2][H], shd[2][H];
    #pragma unroll
    for(int h=0;h<H;h++){
        float v = ps[h], w2 = pd[h];
        #pragma unroll
        for(int off=32; off; off>>=1){ v += __shfl_down(v, off); w2 += __shfl_down(w2, off); }
        if(lane==0){ shs[wv][h]=v; shd[wv][h]=w2; }
    }
    __syncthreads();
    if(t < H){
        asrc[(size_t)node*H + t] = shs[0][t] + shs[1][t];
        adst[(size_t)node*H + t] = shd[0][t] + shd[1][t];
    }
}

// ---------------- aggregation: wave-split edges + float4 gather + LDS cross-wave reduce ----------------
template<int H, int C>
__global__ __launch_bounds__(256) void agg_kernel(const float* __restrict__ hbuf,
                                                  const float* __restrict__ asrc,
                                                  const float* __restrict__ adst,
                                                  const int* __restrict__ rowp,
                                                  const int* __restrict__ colsrc,
                                                  const float* __restrict__ bias,
                                                  short* __restrict__ gh, short* __restrict__ gl, int n){
    constexpr int F = H*C;
    constexpr int PER = F/64;      // floats per lane covering a full row (16 or 8)
    constexpr int PERV = PER/4;    // float4 per lane (4 or 2)
    int node = blockIdx.x;
    int t = threadIdx.x;
    const int w = t >> 6, l = t & 63;
    __shared__ float sh_ee[64][H];
    __shared__ int   sh_src[64];
    __shared__ float sh_adst[H];
    __shared__ float sh_red[256];
    __shared__ float sh_denom[H];
    __shared__ float red[4][F];
    if(t < H) sh_adst[t] = adst[(size_t)node*H + t];
    int beg = rowp[node], end = rowp[node+1];
    float acc[PER];
    #pragma unroll
    for(int k=0;k<PER;k++) acc[k]=0.f;
    float dpart = 0.f;
    const int hh = t % H;          // constant per thread (256 % H == 0)
    for(int base=beg; base<end; base+=64){
        int clen = min(64, end-base);
        __syncthreads();           // protect prev chunk's sh_ee/sh_src reads
        if(t < clen) sh_src[t] = colsrc[base + t];
        int items = clen * H;
        for(int it=t; it<items; it+=256){
            int j = it / H;
            int s = colsrc[base + j];
            float e = asrc[(size_t)s*H + hh] + sh_adst[hh];
            e = (e > 0.f) ? e : 0.2f*e;
            float ee = expf(e);
            sh_ee[j][hh] = ee;
            dpart += ee;
        }
        __syncthreads();
        // wave w handles edges j = w, w+4, ... ; lane covers full row via float4
        for(int j=w; j<clen; j+=4){
            int s = sh_src[j];
            const float4* hrow = (const float4*)(hbuf + (size_t)s*F);
            #pragma unroll
            for(int k=0;k<PERV;k++){
                float4 v = hrow[l + 64*k];
                float ee = sh_ee[j][(4*(l + 64*k))/C];
                acc[4*k+0] += ee * v.x;
                acc[4*k+1] += ee * v.y;
                acc[4*k+2] += ee * v.z;
                acc[4*k+3] += ee * v.w;
            }
        }
    }
    // cross-wave reduce of acc via LDS
    #pragma unroll
    for(int k=0;k<PERV;k++){
        float4 v = { acc[4*k+0], acc[4*k+1], acc[4*k+2], acc[4*k+3] };
        *(float4*)&red[w][4*(l + 64*k)] = v;
    }
    sh_red[t] = dpart;
    __syncthreads();
    if(t < H){
        float s = 0.f;
        for(int i=t; i<256; i+=H) s += sh_red[i];
        sh_denom[t] = s;
    }
    __syncthreads();
    #pragma unroll
    for(int k=0;k<F/256;k++){
        int f = t + k*256;
        float v = red[0][f] + red[1][f] + red[2][f] + red[3][f];
        float denom = sh_denom[f / C] + 1e-16f;
        v = fmaxf(v/denom + bias[f], 0.f);
        short hv = f2bf(v);
        gh[(size_t)node*F + f] = hv;
        gl[(size_t)node*F + f] = f2bf(v - bf2f(hv));
    }
}

// ---------------- classifier: out[n,3] = h[n,:512] @ Wc + bc ----------------
__global__ __launch_bounds__(256) void cls_kernel(const float* __restrict__ h, const float* __restrict__ Wc,
                                                  const float* __restrict__ bc, float* __restrict__ out, int n){
    int node = blockIdx.x*4 + (threadIdx.x >> 6);
    int lane = threadIdx.x & 63;
    if(node >= n) return;
    float s0=0.f, s1=0.f, s2=0.f;
    const float* hr = h + (size_t)node*INT_DIM;
    for(int k=lane; k<INT_DIM; k+=64){
        float v = hr[k];
        s0 += v * Wc[k*3+0];
        s1 += v * Wc[k*3+1];
        s2 += v * Wc[k*3+2];
    }
    #pragma unroll
    for(int off=32; off; off>>=1){
        s0 += __shfl_down(s0, off);
        s1 += __shfl_down(s1, off);
        s2 += __shfl_down(s2, off);
    }
    if(lane==0){
        out[(size_t)node*3+0] = s0 + bc[0];
        out[(size_t)node*3+1] = s1 + bc[1];
        out[(size_t)node*3+2] = s2 + bc[2];
    }
}

extern "C" void kernel_launch(void* const* d_in, const int* in_sizes, int n_in,
                              void* d_out, int out_size, void* d_ws, size_t ws_size,
                              hipStream_t stream){
    const float* x      = (const float*)d_in[0];
    const int*   ei     = (const int*)d_in[1];
    const float* W1     = (const float*)d_in[2];
    const float* a_src1 = (const float*)d_in[3];
    const float* a_dst1 = (const float*)d_in[4];
    const float* b1     = (const float*)d_in[5];
    const float* W2     = (const float*)d_in[6];
    const float* a_src2 = (const float*)d_in[7];
    const float* a_dst2 = (const float*)d_in[8];
    const float* b2     = (const float*)d_in[9];
    const float* W3     = (const float*)d_in[10];
    const float* a_src3 = (const float*)d_in[11];
    const float* a_dst3 = (const float*)d_in[12];
    const float* b3     = (const float*)d_in[13];
    const float* Wl     = (const float*)d_in[14];
    const float* bl     = (const float*)d_in[15];
    const float* Wc     = (const float*)d_in[16];
    const float* bc     = (const float*)d_in[17];
    float* out = (float*)d_out;

    const int* src = ei;
    const int* dst = ei + EE;

    // workspace carve
    char* p = (char*)d_ws;
    float* hbuf = (float*)p;  p += (size_t)MPAD*F1*4;   // 41.4 MB
    short* g_hi = (short*)p;  p += (size_t)MPAD*F1*2;   // 20.7 MB
    short* g_lo = (short*)p;  p += (size_t)MPAD*F1*2;   // 20.7 MB
    short* wt_h = (short*)p;  p += (size_t)F1*F1*2;     // 2.1 MB
    short* wt_l = (short*)p;  p += (size_t)F1*F1*2;     // 2.1 MB
    float* asrc = (float*)p;  p += (size_t)NN*HEADS*4;
    float* adst = (float*)p;  p += (size_t)NN*HEADS*4;
    int* cnt    = (int*)p;    p += NN*4;
    int* rowp   = (int*)p;    p += (NN+1)*4;
    int* cursor = (int*)p;    p += NN*4;
    int* colsrc = (int*)p;    p += EE*4;
    // x split overlays g region (g written only after GEMM1 consumed xs)
    short* xs_h = g_hi;
    short* xs_l = g_lo;

    // ---- CSR build (by dst) ----
    hipMemsetAsync(cnt, 0, NN*sizeof(int), stream);
    count_kernel<<<(EE+255)/256, 256, 0, stream>>>(dst, EE, cnt);
    scan_kernel<<<1, 256, 0, stream>>>(cnt, rowp, cursor, NN);
    fill_kernel<<<(EE+255)/256, 256, 0, stream>>>(src, dst, EE, cursor, colsrc);

    // ---- Layer 1 ----
    split_rows_kernel<<<(NN*IN_DIM/4 + 255)/256, 256, 0, stream>>>(x, xs_h, xs_l, NN*IN_DIM/4);
    splitT_kernel<<<dim3(F1/32, IN_DIM/32), 256, 0, stream>>>(W1, wt_h, wt_l, IN_DIM, F1);
    mfma_gemm_kernel<0><<<(F1/128)*(MPAD/128), 256, 0, stream>>>(xs_h, xs_l, wt_h, wt_l, nullptr, hbuf, F1, IN_DIM, F1/128);
    alpha_kernel<HEADS, HID><<<NN, 128, 0, stream>>>(hbuf, a_src1, a_dst1, asrc, adst, NN);
    agg_kernel<HEADS, HID><<<NN, 256, 0, stream>>>(hbuf, asrc, adst, rowp, colsrc, b1, g_hi, g_lo, NN);

    // ---- Layer 2 ----
    splitT_kernel<<<dim3(F1/32, F1/32), 256, 0, stream>>>(W2, wt_h, wt_l, F1, F1);
    mfma_gemm_kernel<0><<<(F1/128)*(MPAD/128), 256, 0, stream>>>(g_hi, g_lo, wt_h, wt_l, nullptr, hbuf, F1, F1, F1/128);
    alpha_kernel<HEADS, HID><<<NN, 128, 0, stream>>>(hbuf, a_src2, a_dst2, asrc, adst, NN);
    agg_kernel<HEADS, HID><<<NN, 256, 0, stream>>>(hbuf, asrc, adst, rowp, colsrc, b2, g_hi, g_lo, NN);

    // ---- Layer 3 (heads=1, ch=512) ----
    splitT_kernel<<<dim3(INT_DIM/32, F1/32), 256, 0, stream>>>(W3, wt_h, wt_l, F1, INT_DIM);
    mfma_gemm_kernel<0><<<(INT_DIM/128)*(MPAD/128), 256, 0, stream>>>(g_hi, g_lo, wt_h, wt_l, nullptr, hbuf, INT_DIM, F1, INT_DIM/128);
    alpha_kernel<1, INT_DIM><<<NN, 128, 0, stream>>>(hbuf, a_src3, a_dst3, asrc, adst, NN);
    agg_kernel<1, INT_DIM><<<NN, 256, 0, stream>>>(hbuf, asrc, adst, rowp, colsrc, b3, g_hi, g_lo, NN);

    // ---- Linear: relu(g3 @ Wl + bl) ----
    splitT_kernel<<<dim3(INT_DIM/32, INT_DIM/32), 256, 0, stream>>>(Wl, wt_h, wt_l, INT_DIM, INT_DIM);
    mfma_gemm_kernel<1><<<(INT_DIM/128)*(MPAD/128), 256, 0, stream>>>(g_hi, g_lo, wt_h, wt_l, bl, hbuf, INT_DIM, INT_DIM, INT_DIM/128);

    // ---- Classifier ----
    cls_kernel<<<(NN+3)/4, 256, 0, stream>>>(hbuf, Wc, bc, out, NN);
}

// Round 5
// 472.328 us; speedup vs baseline: 2.2216x; 1.1504x over previous
//
#include <hip/hip_runtime.h>
#include <hip/hip_bf16.h>

// Problem constants
#define NN 10000
#define EE 160000
#define IN_DIM 128
#define HID 128
#define HEADS 8
#define F1 (HEADS*HID)   // 1024
#define INT_DIM 512
#define OUT_DIM 3
#define MPAD 10112       // 79 * 128

typedef __attribute__((ext_vector_type(8))) short bf16x8;
typedef __attribute__((ext_vector_type(4))) float f32x4;

__device__ inline short f2bf(float v){
    union { __hip_bfloat16 b; short s; } u;
    u.b = __float2bfloat16(v);
    return u.s;
}
__device__ inline float bf2f(short s){
    union { short s; __hip_bfloat16 b; } u;
    u.s = s;
    return __bfloat162float(u.b);
}

// ---------------- CSR build ----------------
__global__ __launch_bounds__(256) void count_kernel(const int* __restrict__ dst, int E, int* __restrict__ cnt){
    int e = blockIdx.x*256 + threadIdx.x;
    if(e < E) atomicAdd(&cnt[dst[e]], 1);
}

__global__ __launch_bounds__(256) void scan_kernel(const int* __restrict__ cnt, int* __restrict__ rowp,
                                                   int* __restrict__ cursor, int n){
    __shared__ int sh[256];
    __shared__ int stotal;
    int t = threadIdx.x;
    if(t==0) stotal = 0;
    __syncthreads();
    for(int base=0; base<n; base+=256){
        int i = base + t;
        int v = (i<n) ? cnt[i] : 0;
        sh[t] = v;
        __syncthreads();
        #pragma unroll
        for(int off=1; off<256; off<<=1){
            int add = (t>=off) ? sh[t-off] : 0;
            __syncthreads();
            sh[t] += add;
            __syncthreads();
        }
        int excl = sh[t] - v;
        if(i<n){ rowp[i] = stotal + excl; cursor[i] = stotal + excl; }
        int chunk_total = sh[255];
        __syncthreads();
        if(t==0) stotal += chunk_total;
        __syncthreads();
    }
    if(t==0) rowp[n] = stotal;
}

__global__ __launch_bounds__(256) void fill_kernel(const int* __restrict__ src, const int* __restrict__ dst,
                                                   int E, int* __restrict__ cursor, int* __restrict__ colsrc){
    int e = blockIdx.x*256 + threadIdx.x;
    if(e < E){
        int d = dst[e];
        int pos = atomicAdd(&cursor[d], 1);
        colsrc[pos] = src[e];
    }
}

// ---------------- split + transpose weights: B[K,N] fp32 -> T_hi/T_lo [N,K] bf16 ----------------
__global__ __launch_bounds__(256) void splitT_kernel(const float* __restrict__ B, short* __restrict__ Th,
                                                     short* __restrict__ Tl, int K, int N){
    __shared__ float tile[32][33];
    const int tx = threadIdx.x & 31, ty = threadIdx.x >> 5;   // 32 x 8
    const int n0 = blockIdx.x * 32, k0 = blockIdx.y * 32;
    #pragma unroll
    for(int i = 0; i < 32; i += 8)
        tile[ty + i][tx] = B[(size_t)(k0 + ty + i) * N + n0 + tx];
    __syncthreads();
    #pragma unroll
    for(int i = 0; i < 32; i += 8){
        int n = ty + i;
        float v = tile[tx][n];             // = B[k0+tx][n0+n]
        short hv = f2bf(v);
        Th[(size_t)(n0 + n) * K + k0 + tx] = hv;
        Tl[(size_t)(n0 + n) * K + k0 + tx] = f2bf(v - bf2f(hv));
    }
}

// ---------------- aw1[j][k] = sum_c a[j][c] * W1[k, hj*128+c]  (j<8: a_src, j>=8: a_dst) ----------------
__global__ __launch_bounds__(256) void aw1_kernel(const float* __restrict__ W1,
                                                  const float* __restrict__ a_src,
                                                  const float* __restrict__ a_dst,
                                                  float* __restrict__ aw){
    int idx = blockIdx.x*256 + threadIdx.x;
    if(idx >= 16*IN_DIM) return;
    int j = idx >> 7, k = idx & 127;
    int hj = j & 7;
    const float* av = (j < 8 ? a_src : a_dst) + hj*HID;
    const float* wr = W1 + (size_t)k*F1 + hj*HID;
    float s = 0.f;
    #pragma unroll 4
    for(int c = 0; c < HID; c++) s += av[c] * wr[c];
    aw[idx] = s;
}

// ---------------- alpha1[n, j] = x[n,:] @ aw[j,:]  -> asrc/adst [NN,8] ----------------
__global__ __launch_bounds__(256) void alpha1_kernel(const float* __restrict__ x,
                                                     const float* __restrict__ aw,
                                                     float* __restrict__ asrc, float* __restrict__ adst){
    __shared__ float xs[16][128];
    __shared__ float aws[16][128];
    int t = threadIdx.x;
    int nb = blockIdx.x * 16;
    for(int i = t; i < 16*128; i += 256){
        xs[i >> 7][i & 127] = x[(size_t)nb*128 + i];
        aws[i >> 7][i & 127] = aw[i];
    }
    __syncthreads();
    int nl = t >> 4, j = t & 15;
    float s = 0.f;
    #pragma unroll 4
    for(int c = 0; c < 128; c++) s += xs[nl][c] * aws[j][c];
    int node = nb + nl;
    if(j < 8) asrc[node*8 + j] = s;
    else      adst[node*8 + (j-8)] = s;
}

// ---------------- agg1: per-head softmax-agg of RAW x (128-dim gather), out split [N, 8*128] ----------------
__global__ __launch_bounds__(64) void agg1_kernel(const float* __restrict__ x,
                                                  const float* __restrict__ asrc,
                                                  const float* __restrict__ adst,
                                                  const int* __restrict__ rowp,
                                                  const int* __restrict__ colsrc,
                                                  short* __restrict__ oh, short* __restrict__ ol){
    int node = blockIdx.x;
    int l = threadIdx.x;
    __shared__ float sh_ee[64][8];
    __shared__ int   sh_src[64];
    __shared__ float dnm[8];
    int beg = rowp[node], end = rowp[node+1];
    float rd = adst[node*8 + (l & 7)];
    float acc0[8], acc1[8];
    #pragma unroll
    for(int h=0;h<8;h++){ acc0[h]=0.f; acc1[h]=0.f; }
    float dpart = 0.f;
    for(int base=beg; base<end; base+=64){
        int clen = min(64, end-base);
        __syncthreads();
        if(l < clen) sh_src[l] = colsrc[base + l];
        for(int it=l; it<clen*8; it+=64){
            int j = it >> 3, hh = l & 7;
            int s = colsrc[base + j];
            float e = asrc[s*8 + hh] + rd;
            e = (e > 0.f) ? e : 0.2f*e;
            float ee = expf(e);
            sh_ee[j][hh] = ee;
            dpart += ee;
        }
        __syncthreads();
        for(int j=0;j<clen;j++){
            int s = sh_src[j];
            float2 xv = ((const float2*)(x + (size_t)s*128))[l];
            #pragma unroll
            for(int h=0;h<8;h++){
                float w = sh_ee[j][h];
                acc0[h] += w * xv.x;
                acc1[h] += w * xv.y;
            }
        }
    }
    #pragma unroll
    for(int off=8; off<64; off<<=1) dpart += __shfl_xor(dpart, off);
    __syncthreads();
    if(l < 8) dnm[l] = dpart;
    __syncthreads();
    #pragma unroll
    for(int h=0;h<8;h++){
        float dn = dnm[h] + 1e-16f;
        float v0 = acc0[h]/dn, v1 = acc1[h]/dn;
        short h0 = f2bf(v0), h1 = f2bf(v1);
        short2 hi = { h0, h1 };
        short2 lo = { f2bf(v0 - bf2f(h0)), f2bf(v1 - bf2f(h1)) };
        size_t off = (size_t)node*F1 + h*128 + 2*l;
        *(short2*)(oh + off) = hi;
        *(short2*)(ol + off) = lo;
    }
}

// ---------------- agg2: softmax-agg of h2 fp32 [1024], +bias +relu, out split ----------------
__global__ __launch_bounds__(64) void agg2_kernel(const float* __restrict__ hbuf,
                                                  const float* __restrict__ asrc,
                                                  const float* __restrict__ adst,
                                                  const int* __restrict__ rowp,
                                                  const int* __restrict__ colsrc,
                                                  const float* __restrict__ bias,
                                                  short* __restrict__ oh, short* __restrict__ ol){
    int node = blockIdx.x;
    int l = threadIdx.x;
    __shared__ float sh_ee[64][8];
    __shared__ int   sh_src[64];
    __shared__ float dnm[8];
    int beg = rowp[node], end = rowp[node+1];
    float rd = adst[node*8 + (l & 7)];
    float acc[16];
    #pragma unroll
    for(int k=0;k<16;k++) acc[k]=0.f;
    float dpart = 0.f;
    for(int base=beg; base<end; base+=64){
        int clen = min(64, end-base);
        __syncthreads();
        if(l < clen) sh_src[l] = colsrc[base + l];
        for(int it=l; it<clen*8; it+=64){
            int j = it >> 3, hh = l & 7;
            int s = colsrc[base + j];
            float e = asrc[s*8 + hh] + rd;
            e = (e > 0.f) ? e : 0.2f*e;
            float ee = expf(e);
            sh_ee[j][hh] = ee;
            dpart += ee;
        }
        __syncthreads();
        for(int j=0;j<clen;j++){
            int s = sh_src[j];
            const float4* hr = (const float4*)(hbuf + (size_t)s*F1);
            #pragma unroll
            for(int k=0;k<4;k++){
                float4 v = hr[l + 64*k];
                float w = sh_ee[j][2*k + (l>>5)];
                acc[4*k+0] += w*v.x; acc[4*k+1] += w*v.y;
                acc[4*k+2] += w*v.z; acc[4*k+3] += w*v.w;
            }
        }
    }
    #pragma unroll
    for(int off=8; off<64; off<<=1) dpart += __shfl_xor(dpart, off);
    __syncthreads();
    if(l < 8) dnm[l] = dpart;
    __syncthreads();
    #pragma unroll
    for(int k=0;k<4;k++){
        float dn = dnm[2*k + (l>>5)] + 1e-16f;
        int f = 4*(l + 64*k);
        float4 bb = *(const float4*)(bias + f);
        float v0 = fmaxf(acc[4*k+0]/dn + bb.x, 0.f);
        float v1 = fmaxf(acc[4*k+1]/dn + bb.y, 0.f);
        float v2 = fmaxf(acc[4*k+2]/dn + bb.z, 0.f);
        float v3 = fmaxf(acc[4*k+3]/dn + bb.w, 0.f);
        short h0=f2bf(v0), h1=f2bf(v1), h2=f2bf(v2), h3=f2bf(v3);
        short4 hi = { h0, h1, h2, h3 };
        short4 lo = { f2bf(v0-bf2f(h0)), f2bf(v1-bf2f(h1)), f2bf(v2-bf2f(h2)), f2bf(v3-bf2f(h3)) };
        size_t off = (size_t)node*F1 + f;
        *(short4*)(oh + off) = hi;
        *(short4*)(ol + off) = lo;
    }
}

// ---------------- agg3: softmax-agg of h3 fp32 [512] H=1, +bias +relu, out split ----------------
__global__ __launch_bounds__(64) void agg3_kernel(const float* __restrict__ hbuf,
                                                  const float* __restrict__ asrc,
                                                  const float* __restrict__ adst,
                                                  const int* __restrict__ rowp,
                                                  const int* __restrict__ colsrc,
                                                  const float* __restrict__ bias,
                                                  short* __restrict__ oh, short* __restrict__ ol){
    int node = blockIdx.x;
    int l = threadIdx.x;
    __shared__ float sh_ee[64];
    __shared__ int   sh_src[64];
    int beg = rowp[node], end = rowp[node+1];
    float rd = adst[node];
    float acc[8];
    #pragma unroll
    for(int k=0;k<8;k++) acc[k]=0.f;
    float dpart = 0.f;
    for(int base=beg; base<end; base+=64){
        int clen = min(64, end-base);
        __syncthreads();
        if(l < clen){
            int s = colsrc[base + l];
            sh_src[l] = s;
            float e = asrc[s] + rd;
            e = (e > 0.f) ? e : 0.2f*e;
            float ee = expf(e);
            sh_ee[l] = ee;
            dpart += ee;
        }
        __syncthreads();
        for(int j=0;j<clen;j++){
            int s = sh_src[j];
            const float4* hr = (const float4*)(hbuf + (size_t)s*INT_DIM);
            float w = sh_ee[j];
            #pragma unroll
            for(int k=0;k<2;k++){
                float4 v = hr[l + 64*k];
                acc[4*k+0] += w*v.x; acc[4*k+1] += w*v.y;
                acc[4*k+2] += w*v.z; acc[4*k+3] += w*v.w;
            }
        }
    }
    #pragma unroll
    for(int off=1; off<64; off<<=1) dpart += __shfl_xor(dpart, off);
    float dn = dpart + 1e-16f;
    #pragma unroll
    for(int k=0;k<2;k++){
        int f = 4*(l + 64*k);
        float4 bb = *(const float4*)(bias + f);
        float v0 = fmaxf(acc[4*k+0]/dn + bb.x, 0.f);
        float v1 = fmaxf(acc[4*k+1]/dn + bb.y, 0.f);
        float v2 = fmaxf(acc[4*k+2]/dn + bb.z, 0.f);
        float v3 = fmaxf(acc[4*k+3]/dn + bb.w, 0.f);
        short h0=f2bf(v0), h1=f2bf(v1), h2=f2bf(v2), h3=f2bf(v3);
        short4 hi = { h0, h1, h2, h3 };
        short4 lo = { f2bf(v0-bf2f(h0)), f2bf(v1-bf2f(h1)), f2bf(v2-bf2f(h2)), f2bf(v3-bf2f(h3)) };
        size_t off = (size_t)node*INT_DIM + f;
        *(short4*)(oh + off) = hi;
        *(short4*)(ol + off) = lo;
    }
}

// ---------------- fused split-bf16 MFMA GEMM (generalized: lda/ldb/ldc, blockIdx.z offsets) ----------------
// C = (Ah+Al) @ (Bh+Bl)^T via AhBh + AhBl + AlBh in ONE K-loop (48 MFMA / K-step).
template<int FUSE, int SPLIT>
__global__ __launch_bounds__(256) void mfma_gemm_kernel(
    const short* __restrict__ Ah, const short* __restrict__ Al, int lda, int za,
    const short* __restrict__ Bh, const short* __restrict__ Bl, int ldb, int zb,
    const float* __restrict__ bias, float* __restrict__ C,
    short* __restrict__ Gh, short* __restrict__ Gl, int ldc, int zc,
    int K, int gx)
{
    __shared__ short lAh[128*32];   // 8 KB each
    __shared__ short lAl[128*32];
    __shared__ short lBh[128*32];
    __shared__ short lBl[128*32];
    const int tid  = threadIdx.x;
    const int lane = tid & 63;
    const int w    = tid >> 6;
    const int wm   = w >> 1, wn = w & 1;
    const int z    = blockIdx.z;

    // XCD-bijective swizzle
    const int nwg = gridDim.x;
    const int q = nwg >> 3, r = nwg & 7;
    const int xcd = blockIdx.x & 7, idx = blockIdx.x >> 3;
    const int wgid = (xcd < r ? xcd*(q+1) : r*(q+1) + (xcd-r)*q) + idx;
    const int row0 = (wgid / gx) * 128, col0 = (wgid % gx) * 128;

    f32x4 acc[4][4];
    #pragma unroll
    for(int i=0;i<4;i++)
        #pragma unroll
        for(int j=0;j<4;j++) acc[i][j] = (f32x4){0.f,0.f,0.f,0.f};

    const int r1 = tid >> 2,  s1 = (tid & 3) ^ (r1 & 3);
    const int r2 = r1 + 64,   s2 = (tid & 3) ^ (r2 & 3);
    const size_t aoff1 = (size_t)(row0 + r1) * lda + (size_t)z*za + s1 * 8;
    const size_t aoff2 = (size_t)(row0 + r2) * lda + (size_t)z*za + s2 * 8;
    const size_t boff1 = (size_t)(col0 + r1) * ldb + (size_t)z*zb + s1 * 8;
    const size_t boff2 = (size_t)(col0 + r2) * ldb + (size_t)z*zb + s2 * 8;

    typedef __attribute__((address_space(3))) char lds_char;
    lds_char* dAh1 = (lds_char*)(&lAh[0]) + w*1024;  lds_char* dAh2 = dAh1 + 4096;
    lds_char* dAl1 = (lds_char*)(&lAl[0]) + w*1024;  lds_char* dAl2 = dAl1 + 4096;
    lds_char* dBh1 = (lds_char*)(&lBh[0]) + w*1024;  lds_char* dBh2 = dBh1 + 4096;
    lds_char* dBl1 = (lds_char*)(&lBl[0]) + w*1024;  lds_char* dBl2 = dBl1 + 4096;

    int arow[4], brow[4];
    const int slotx = ((lane >> 4) ^ (lane & 3)) << 4;
    #pragma unroll
    for(int i=0;i<4;i++){
        arow[i] = (wm*64 + i*16 + (lane & 15)) * 64 + slotx;
        brow[i] = (wn*64 + i*16 + (lane & 15)) * 64 + slotx;
    }

    #pragma unroll 1
    for(int k0 = 0; k0 < K; k0 += 32){
        __syncthreads();
        #define GLDS(src, dst) __builtin_amdgcn_global_load_lds( \
            (__attribute__((address_space(1))) void*)(src), \
            (__attribute__((address_space(3))) void*)(dst), 16, 0, 0)
        GLDS(Ah + aoff1 + k0, dAh1);  GLDS(Ah + aoff2 + k0, dAh2);
        GLDS(Al + aoff1 + k0, dAl1);  GLDS(Al + aoff2 + k0, dAl2);
        GLDS(Bh + boff1 + k0, dBh1);  GLDS(Bh + boff2 + k0, dBh2);
        GLDS(Bl + boff1 + k0, dBl1);  GLDS(Bl + boff2 + k0, dBl2);
        #undef GLDS
        __syncthreads();
        bf16x8 afh[4], afl[4];
        #pragma unroll
        for(int i=0;i<4;i++){
            afh[i] = *(const bf16x8*)((const char*)lAh + arow[i]);
            afl[i] = *(const bf16x8*)((const char*)lAl + arow[i]);
        }
        #pragma unroll
        for(int j=0;j<4;j++){
            bf16x8 bh = *(const bf16x8*)((const char*)lBh + brow[j]);
            bf16x8 bl = *(const bf16x8*)((const char*)lBl + brow[j]);
            #pragma unroll
            for(int i=0;i<4;i++){
                acc[i][j] = __builtin_amdgcn_mfma_f32_16x16x32_bf16(afh[i], bh, acc[i][j], 0, 0, 0);
                acc[i][j] = __builtin_amdgcn_mfma_f32_16x16x32_bf16(afh[i], bl, acc[i][j], 0, 0, 0);
                acc[i][j] = __builtin_amdgcn_mfma_f32_16x16x32_bf16(afl[i], bh, acc[i][j], 0, 0, 0);
            }
        }
    }

    // epilogue: C/D layout col=lane&15, row=(lane>>4)*4+reg
    #pragma unroll
    for(int i=0;i<4;i++){
        const int rr = row0 + wm*64 + i*16 + ((lane >> 4) << 2);
        #pragma unroll
        for(int j=0;j<4;j++){
            const int gc = z*zc + col0 + wn*64 + j*16 + (lane & 15);
            float b = FUSE ? bias[gc] : 0.f;
            #pragma unroll
            for(int rg=0;rg<4;rg++){
                float v = acc[i][j][rg];
                if(FUSE) v = fmaxf(v + b, 0.f);
                if(SPLIT){
                    short hv = f2bf(v);
                    Gh[(size_t)(rr + rg) * ldc + gc] = hv;
                    Gl[(size_t)(rr + rg) * ldc + gc] = f2bf(v - bf2f(hv));
                } else {
                    C[(size_t)(rr + rg) * ldc + gc] = v;
                }
            }
        }
    }
}

// ---------------- alpha: per-node per-head dot(h[n,h,:], a[h,:])  (project-first layers) ----------------
template<int H, int C>
__global__ __launch_bounds__(128) void alpha_kernel(const float* __restrict__ hbuf,
                                                    const float* __restrict__ a_src,
                                                    const float* __restrict__ a_dst,
                                                    float* __restrict__ asrc, float* __restrict__ adst, int n){
    constexpr int F = H*C;
    int node = blockIdx.x;
    int t = threadIdx.x;          // 128 threads
    float ps[H], pd[H];
    #pragma unroll
    for(int h=0;h<H;h++){ ps[h]=0.f; pd[h]=0.f; }
    #pragma unroll
    for(int k=0;k<F/128;k++){
        int idx = t + k*128;
        int h = (k*128)/C;
        float v = hbuf[(size_t)node*F + idx];
        ps[h] += v * a_src[idx];
        pd[h] += v * a_dst[idx];
    }
    int lane = t & 63, wv = t >> 6;
    __shared__ float shs[2][H], shd[2][H];
    #pragma unroll
    for(int h=0;h<H;h++){
        float v = ps[h], w2 = pd[h];
        #pragma unroll
        for(int off=32; off; off>>=1){ v += __shfl_down(v, off); w2 += __shfl_down(w2, off); }
        if(lane==0){ shs[wv][h]=v; shd[wv][h]=w2; }
    }
    __syncthreads();
    if(t < H){
        asrc[(size_t)node*H + t] = shs[0][t] + shs[1][t];
        adst[(size_t)node*H + t] = shd[0][t] + shd[1][t];
    }
}

// ---------------- classifier: out[n,3] = h[n,:512] @ Wc + bc ----------------
__global__ __launch_bounds__(256) void cls_kernel(const float* __restrict__ h, const float* __restrict__ Wc,
                                                  const float* __restrict__ bc, float* __restrict__ out, int n){
    int node = blockIdx.x*4 + (threadIdx.x >> 6);
    int lane = threadIdx.x & 63;
    if(node >= n) return;
    float s0=0.f, s1=0.f, s2=0.f;
    const float* hr = h + (size_t)node*INT_DIM;
    for(int k=lane; k<INT_DIM; k+=64){
        float v = hr[k];
        s0 += v * Wc[k*3+0];
        s1 += v * Wc[k*3+1];
        s2 += v * Wc[k*3+2];
    }
    #pragma unroll
    for(int off=32; off; off>>=1){
        s0 += __shfl_down(s0, off);
        s1 += __shfl_down(s1, off);
        s2 += __shfl_down(s2, off);
    }
    if(lane==0){
        out[(size_t)node*3+0] = s0 + bc[0];
        out[(size_t)node*3+1] = s1 + bc[1];
        out[(size_t)node*3+2] = s2 + bc[2];
    }
}

extern "C" void kernel_launch(void* const* d_in, const int* in_sizes, int n_in,
                              void* d_out, int out_size, void* d_ws, size_t ws_size,
                              hipStream_t stream){
    const float* x      = (const float*)d_in[0];
    const int*   ei     = (const int*)d_in[1];
    const float* W1     = (const float*)d_in[2];
    const float* a_src1 = (const float*)d_in[3];
    const float* a_dst1 = (const float*)d_in[4];
    const float* b1     = (const float*)d_in[5];
    const float* W2     = (const float*)d_in[6];
    const float* a_src2 = (const float*)d_in[7];
    const float* a_dst2 = (const float*)d_in[8];
    const float* b2     = (const float*)d_in[9];
    const float* W3     = (const float*)d_in[10];
    const float* a_src3 = (const float*)d_in[11];
    const float* a_dst3 = (const float*)d_in[12];
    const float* b3     = (const float*)d_in[13];
    const float* Wl     = (const float*)d_in[14];
    const float* bl     = (const float*)d_in[15];
    const float* Wc     = (const float*)d_in[16];
    const float* bc     = (const float*)d_in[17];
    float* out = (float*)d_out;

    const int* src = ei;
    const int* dst = ei + EE;

    // workspace carve: two big regions (41.4 MB each) + weights + small
    char* p = (char*)d_ws;
    char* regA = p;  p += (size_t)MPAD*F1*4;            // pair {ph,pl} OR fp32 buffer
    char* regB = p;  p += (size_t)MPAD*F1*4;            // pair {qh,ql}
    short* wt_h = (short*)p;  p += (size_t)F1*F1*2;     // 2.1 MB
    short* wt_l = (short*)p;  p += (size_t)F1*F1*2;     // 2.1 MB
    float* aw1  = (float*)p;  p += 16*IN_DIM*4;
    float* asrc = (float*)p;  p += (size_t)NN*HEADS*4;
    float* adst = (float*)p;  p += (size_t)NN*HEADS*4;
    int* cnt    = (int*)p;    p += NN*4;
    int* rowp   = (int*)p;    p += (NN+1)*4;
    int* cursor = (int*)p;    p += NN*4;
    int* colsrc = (int*)p;    p += EE*4;

    short* ph = (short*)regA;  short* pl = ph + (size_t)MPAD*F1;
    float* Af = (float*)regA;
    short* qh = (short*)regB;  short* ql = qh + (size_t)MPAD*F1;

    // ---- CSR build (by dst) ----
    hipMemsetAsync(cnt, 0, NN*sizeof(int), stream);
    count_kernel<<<(EE+255)/256, 256, 0, stream>>>(dst, EE, cnt);
    scan_kernel<<<1, 256, 0, stream>>>(cnt, rowp, cursor, NN);
    fill_kernel<<<(EE+255)/256, 256, 0, stream>>>(src, dst, EE, cursor, colsrc);

    // ---- Layer 1 (agg-first via linearity) ----
    splitT_kernel<<<dim3(F1/32, IN_DIM/32), 256, 0, stream>>>(W1, wt_h, wt_l, IN_DIM, F1);
    aw1_kernel<<<8, 256, 0, stream>>>(W1, a_src1, a_dst1, aw1);
    alpha1_kernel<<<NN/16, 256, 0, stream>>>(x, aw1, asrc, adst);
    agg1_kernel<<<NN, 64, 0, stream>>>(x, asrc, adst, rowp, colsrc, ph, pl);
    // out1 = relu(xa @ W1 + b1), block-diagonal per head, split output -> regB
    mfma_gemm_kernel<1,1><<<dim3(MPAD/128, 1, HEADS), 256, 0, stream>>>(
        ph, pl, F1, 128,  wt_h, wt_l, IN_DIM, 128*IN_DIM,
        b1, nullptr, qh, ql, F1, 128,  IN_DIM, 1);

    // ---- Layer 2 (project-first) ----
    splitT_kernel<<<dim3(F1/32, F1/32), 256, 0, stream>>>(W2, wt_h, wt_l, F1, F1);
    mfma_gemm_kernel<0,0><<<dim3((F1/128)*(MPAD/128), 1, 1), 256, 0, stream>>>(
        qh, ql, F1, 0,  wt_h, wt_l, F1, 0,
        nullptr, Af, nullptr, nullptr, F1, 0,  F1, F1/128);
    alpha_kernel<HEADS, HID><<<NN, 128, 0, stream>>>(Af, a_src2, a_dst2, asrc, adst, NN);
    agg2_kernel<<<NN, 64, 0, stream>>>(Af, asrc, adst, rowp, colsrc, b2, qh, ql);

    // ---- Layer 3 (project-first, H=1) ----
    splitT_kernel<<<dim3(INT_DIM/32, F1/32), 256, 0, stream>>>(W3, wt_h, wt_l, F1, INT_DIM);
    mfma_gemm_kernel<0,0><<<dim3((INT_DIM/128)*(MPAD/128), 1, 1), 256, 0, stream>>>(
        qh, ql, F1, 0,  wt_h, wt_l, F1, 0,
        nullptr, Af, nullptr, nullptr, INT_DIM, 0,  F1, INT_DIM/128);
    alpha_kernel<1, INT_DIM><<<NN, 128, 0, stream>>>(Af, a_src3, a_dst3, asrc, adst, NN);
    agg3_kernel<<<NN, 64, 0, stream>>>(Af, asrc, adst, rowp, colsrc, b3, qh, ql);

    // ---- Linear: relu(out3 @ Wl + bl) -> Af fp32 [NN,512] ----
    splitT_kernel<<<dim3(INT_DIM/32, INT_DIM/32), 256, 0, stream>>>(Wl, wt_h, wt_l, INT_DIM, INT_DIM);
    mfma_gemm_kernel<1,0><<<dim3((INT_DIM/128)*(MPAD/128), 1, 1), 256, 0, stream>>>(
        qh, ql, INT_DIM, 0,  wt_h, wt_l, INT_DIM, 0,
        bl, Af, nullptr, nullptr, INT_DIM, 0,  INT_DIM, INT_DIM/128);

    // ---- Classifier ----
    cls_kernel<<<(NN+3)/4, 256, 0, stream>>>(Af, Wc, bc, out, NN);
}